// Round 3
// baseline (1095.556 us; speedup 1.0000x reference)
//
#include <hip/hip_runtime.h>

// Problem: S=512, B=256, I=64, H=512, O=25.
// y depends only on batch row 255 (out[:, -1, :]) and the recurrence is
// per-row independent -> compute only row 255.
//
//   rnn_pre : xi[t][h] = x[t,255,:] . W_ih[h,:] + b_ih[h] + b_hh[h];
//             block (0,0) also re-inits all exchange mailboxes (sign=1 =
//             not-ready for generation 0) -- no reliance on ws poison.
//   rnn_seq : 512 sequential steps h = relu(xi_t + W_hh h_prev) on G_=8
//             blocks (64 rows each, W_hh register-resident, 128 VGPR/thread).
//             Exchange: 32-bit values, generation in the SIGN BIT (relu =>
//             h>=0), double-buffered by s&1, generation (s>>1)&1. Progress
//             invariant bounds skew to <2 steps. REPLICATED per-consumer
//             mailboxes: producer pushes to 7 remote mailboxes; consumer
//             polls only its private region (kills poll-line contention).
//             h double-buffered in LDS -> single __syncthreads per step.
//   rnn_post: y[t] = h_t . W2^T + b2   (512x25)

#define S_ 512
#define B_ 256
#define I_ 64
#define H_ 512
#define O_ 25
#define G_ 8    // blocks in rnn_seq
#define R_ 64   // rows per block (H_/G_)

__global__ __launch_bounds__(256) void rnn_pre(
    const float* __restrict__ x, const float* __restrict__ W_ih,
    const float* __restrict__ b_ih, const float* __restrict__ b_hh,
    float* __restrict__ xi, unsigned* __restrict__ mbox) {
  const int t = blockIdx.x;
  const int tid = threadIdx.x;
  const int o = blockIdx.y * 256 + tid;
  if (t == 0 && blockIdx.y == 0) {
    // init all G_ mailboxes (both buffers) to sign=1 (not-ready for gen 0);
    // kernel boundary makes these visible to rnn_seq.
    for (int j = tid; j < G_ * 2 * H_; j += 256) mbox[j] = 0x80000000u;
  }
  __shared__ float xr[I_];
  if (tid < I_) xr[tid] = x[(t * B_ + (B_ - 1)) * I_ + tid];
  __syncthreads();
  float acc = b_ih[o] + b_hh[o];
  const float4* wp = (const float4*)(W_ih + o * I_);
#pragma unroll
  for (int j = 0; j < I_ / 4; ++j) {
    float4 w4 = wp[j];
    acc += w4.x * xr[4 * j] + w4.y * xr[4 * j + 1] + w4.z * xr[4 * j + 2] +
           w4.w * xr[4 * j + 3];
  }
  xi[t * H_ + o] = acc;
}

__global__ __launch_bounds__(256) void rnn_seq(
    const float* __restrict__ W_hh, const float* __restrict__ xi,
    float* __restrict__ hseq, unsigned* __restrict__ mbox) {
  const int tid = threadIdx.x;
  const int b = blockIdx.x;
  const int row_l = tid >> 2;    // local row 0..63 (4 threads per row, same wave)
  const int q = tid & 3;         // quarter: 128-wide k-chunk
  const int row = b * R_ + row_l;
  const int k0 = q * 128;
  const int own_lo = b * R_;

  __shared__ float h_l[2][H_];   // double-buffered: no read/write race, 1 barrier/step

  // W_hh register-resident: thread holds W_hh[row][k0..k0+127].
  float w[128];
  {
    const float4* wp = (const float4*)(W_hh + row * H_ + k0);
#pragma unroll
    for (int j = 0; j < 32; ++j) {
      float4 v = wp[j];
      w[4 * j] = v.x; w[4 * j + 1] = v.y; w[4 * j + 2] = v.z; w[4 * j + 3] = v.w;
    }
  }
  for (int n = tid; n < H_; n += 256) h_l[0][n] = 0.0f;  // h_{-1} = 0

  const bool fin = (q == 0);     // finalizer lane for this row
  float xiv = fin ? xi[own_lo + row_l] : 0.0f;
  __syncthreads();

  const int n0 = tid, n1 = tid + 256;
  const bool own0 = (n0 >= own_lo && n0 < own_lo + R_);
  const bool own1 = (n1 >= own_lo && n1 < own_lo + R_);
  unsigned* const mb0 = mbox + (b * 2 + 0) * H_;  // my mailbox, buffer 0
  unsigned* const mb1 = mbox + (b * 2 + 1) * H_;  // my mailbox, buffer 1

  for (int s = 0; s < S_; ++s) {
    const float* hr = h_l[s & 1];        // read h_{s-1}
    float* hw = h_l[(s + 1) & 1];        // write h_s (read next step)

    // partial dot: 128 MACs, 4 accumulator chains
    float a0 = 0.f, a1 = 0.f, a2 = 0.f, a3 = 0.f;
    const float4* hp = (const float4*)(hr + k0);
#pragma unroll
    for (int j = 0; j < 32; ++j) {
      float4 hv = hp[j];
      a0 = fmaf(w[4 * j + 0], hv.x, a0);
      a1 = fmaf(w[4 * j + 1], hv.y, a1);
      a2 = fmaf(w[4 * j + 2], hv.z, a2);
      a3 = fmaf(w[4 * j + 3], hv.w, a3);
    }
    float acc = (a0 + a1) + (a2 + a3);
    // fold the 4 quarters (lanes tid^1, tid^2 are the same row, same wave)
    acc += __shfl_xor(acc, 1, 64);
    acc += __shfl_xor(acc, 2, 64);

    const unsigned phase = (unsigned)((s >> 1) & 1);
    const int bsel = s & 1;

    if (fin) {
      float h = fmaxf(acc + xiv, 0.0f);
      hw[row] = h;                        // own rows: LDS-direct, no RTT
      hseq[s * H_ + row] = h;             // for rnn_post
      unsigned pk = __float_as_uint(h) | (phase << 31);
      // push to the 7 remote consumers' private mailboxes
#pragma unroll
      for (int c = 0; c < G_; ++c) {
        if (c != b)
          __hip_atomic_store(&mbox[(c * 2 + bsel) * H_ + row], pk,
                             __ATOMIC_RELAXED, __HIP_MEMORY_SCOPE_AGENT);
      }
    }

    if (s == S_ - 1) break;               // nothing to consume after last step

    // prefetch next step's xi (hidden under poll RTT)
    if (fin) xiv = xi[(s + 1) * H_ + own_lo + row_l];

    // poll MY mailbox only; both entries in flight concurrently
    unsigned* const buf = bsel ? mb1 : mb0;
    bool need0 = !own0, need1 = !own1;
    unsigned p0, p1;
    while (need0 | need1) {
      if (need0)
        p0 = __hip_atomic_load(&buf[n0], __ATOMIC_RELAXED, __HIP_MEMORY_SCOPE_AGENT);
      if (need1)
        p1 = __hip_atomic_load(&buf[n1], __ATOMIC_RELAXED, __HIP_MEMORY_SCOPE_AGENT);
      if (need0 && (p0 >> 31) == phase) {
        hw[n0] = __uint_as_float(p0 & 0x7fffffffu);
        need0 = false;
      }
      if (need1 && (p1 >> 31) == phase) {
        hw[n1] = __uint_as_float(p1 & 0x7fffffffu);
        need1 = false;
      }
    }
    __syncthreads();
  }
}

__global__ __launch_bounds__(256) void rnn_post(
    const float* __restrict__ hseq, const float* __restrict__ W2,
    const float* __restrict__ b2, float* __restrict__ y) {
  const int t = blockIdx.x;
  const int tid = threadIdx.x;
  __shared__ float hl[H_];
  __shared__ float part[256];
  for (int n = tid; n < H_; n += 256) hl[n] = hseq[t * H_ + n];
  __syncthreads();
  const int o = tid >> 3;
  const int seg = tid & 7;
  float acc = 0.0f;
  if (o < O_) {
    const float4* wp = (const float4*)(W2 + o * H_ + seg * 64);
    const float4* hp = (const float4*)(hl + seg * 64);
#pragma unroll
    for (int j = 0; j < 16; ++j) {
      float4 w4 = wp[j];
      float4 h4 = hp[j];
      acc += w4.x * h4.x + w4.y * h4.y + w4.z * h4.z + w4.w * h4.w;
    }
  }
  part[tid] = acc;
  __syncthreads();
  if (tid < O_) {
    float sum = 0.0f;
#pragma unroll
    for (int j = 0; j < 8; ++j) sum += part[tid * 8 + j];
    y[t * O_ + tid] = sum + b2[tid];
  }
}

extern "C" void kernel_launch(void* const* d_in, const int* in_sizes, int n_in,
                              void* d_out, int out_size, void* d_ws, size_t ws_size,
                              hipStream_t stream) {
  const float* x    = (const float*)d_in[0];
  const float* W_ih = (const float*)d_in[1];
  const float* W_hh = (const float*)d_in[2];
  const float* b_ih = (const float*)d_in[3];
  const float* b_hh = (const float*)d_in[4];
  const float* W2   = (const float*)d_in[5];
  const float* b2   = (const float*)d_in[6];
  float* y = (float*)d_out;

  float* xi   = (float*)d_ws;                      // [512*512]
  float* hseq = xi + S_ * H_;                      // [512*512]
  unsigned* mbox = (unsigned*)(hseq + S_ * H_);    // [G_*2*512] mailboxes

  rnn_pre<<<dim3(S_, 2), 256, 0, stream>>>(x, W_ih, b_ih, b_hh, xi, mbox);
  rnn_seq<<<G_, 256, 0, stream>>>(W_hh, xi, hseq, mbox);
  rnn_post<<<S_, 256, 0, stream>>>(hseq, W2, b2, y);
}

// Round 4
// 916.513 us; speedup vs baseline: 1.1954x; 1.1954x over previous
//
#include <hip/hip_runtime.h>

// Problem: S=512, B=256, I=64, H=512, O=25.
// y depends only on batch row 255 (out[:, -1, :]) and the recurrence is
// per-row independent -> compute only row 255.
//
//   rnn_pre : xi[t][h] = x[t,255,:] . W_ih[h,:] + b_ih[h] + b_hh[h];
//             block (0,0) also re-inits all exchange mailboxes.
//   rnn_seq : 512 sequential steps h = relu(xi_t + W_hh h_prev) on G_=16
//             blocks (32 rows each, W_hh register-resident w[64], VGPR~48 --
//             the R2 core, measured 0 LDS conflicts). Exchange: 32-bit
//             values, generation in the SIGN BIT (relu => h>=0, with -0.0
//             guard), double-buffered by s&1, generation (s>>1)&1; progress
//             invariant bounds skew <2 steps. NEW vs R2: REPLICATED
//             per-consumer mailboxes -- producer pushes each row to the 15
//             remote consumers' private buffers; each consumer polls only
//             its own 2KB region (pollers/line 256 -> 16, and publishes no
//             longer queue behind the poll backlog on shared lines).
//   rnn_post: y[t] = h_t . W2^T + b2   (512x25)

#define S_ 512
#define B_ 256
#define I_ 64
#define H_ 512
#define O_ 25
#define G_ 16   // blocks in rnn_seq
#define R_ 32   // rows per block (H_/G_)

__global__ __launch_bounds__(256) void rnn_pre(
    const float* __restrict__ x, const float* __restrict__ W_ih,
    const float* __restrict__ b_ih, const float* __restrict__ b_hh,
    float* __restrict__ xi, unsigned* __restrict__ mbox) {
  const int t = blockIdx.x;
  const int tid = threadIdx.x;
  const int o = blockIdx.y * 256 + tid;
  if (t == 0 && blockIdx.y == 0) {
    // init all G_ consumers' mailboxes (both buffers) to sign=1 (not-ready
    // for generation 0); kernel boundary publishes to rnn_seq.
    for (int j = tid; j < G_ * 2 * H_; j += 256) mbox[j] = 0x80000000u;
  }
  __shared__ float xr[I_];
  if (tid < I_) xr[tid] = x[(t * B_ + (B_ - 1)) * I_ + tid];
  __syncthreads();
  float acc = b_ih[o] + b_hh[o];
  const float4* wp = (const float4*)(W_ih + o * I_);
#pragma unroll
  for (int j = 0; j < I_ / 4; ++j) {
    float4 w4 = wp[j];
    acc += w4.x * xr[4 * j] + w4.y * xr[4 * j + 1] + w4.z * xr[4 * j + 2] +
           w4.w * xr[4 * j + 3];
  }
  xi[t * H_ + o] = acc;
}

__global__ __launch_bounds__(256) void rnn_seq(
    const float* __restrict__ W_hh, const float* __restrict__ xi,
    float* __restrict__ hseq, unsigned* __restrict__ mbox) {
  const int tid = threadIdx.x;
  const int b = blockIdx.x;
  const int r = tid & 31;        // row within block's 32 rows
  const int seg = tid >> 5;      // 0..7 : 64-wide k-chunk
  const int row = b * R_ + r;
  const int k0 = seg * 64;
  const int wave = tid >> 6;
  const int own_lo = b * R_;
  const int own_hi = b * R_ + R_;

  __shared__ float h_l[H_];
  __shared__ float part[4 * R_];

  // W_hh register-resident: thread (r,seg) holds W_hh[row][k0..k0+63].
  float w[64];
  {
    const float4* wp = (const float4*)(W_hh + row * H_ + k0);
#pragma unroll
    for (int j = 0; j < 16; ++j) {
      float4 v = wp[j];
      w[4 * j] = v.x; w[4 * j + 1] = v.y; w[4 * j + 2] = v.z; w[4 * j + 3] = v.w;
    }
  }
  for (int n = tid; n < H_; n += 256) h_l[n] = 0.0f;  // h_{-1} = 0

  // xi for step 0; later steps prefetched during the poll phase.
  float xiv = (tid < R_) ? xi[own_lo + tid] : 0.0f;
  __syncthreads();

  const int n0 = tid, n1 = tid + 256;
  const bool own0 = (n0 >= own_lo && n0 < own_hi);
  const bool own1 = (n1 >= own_lo && n1 < own_hi);

  for (int s = 0; s < S_; ++s) {
    // partial dot, 4 independent accumulator chains (h_l reads: 2 distinct
    // addresses per wave on same banks = 2-way = free)
    float a0 = 0.f, a1 = 0.f, a2 = 0.f, a3 = 0.f;
    const float4* hp = (const float4*)(h_l + k0);
#pragma unroll
    for (int j = 0; j < 16; ++j) {
      float4 hv = hp[j];
      a0 = fmaf(w[4 * j + 0], hv.x, a0);
      a1 = fmaf(w[4 * j + 1], hv.y, a1);
      a2 = fmaf(w[4 * j + 2], hv.z, a2);
      a3 = fmaf(w[4 * j + 3], hv.w, a3);
    }
    float acc = (a0 + a1) + (a2 + a3);
    acc += __shfl_xor(acc, 32, 64);          // fold seg pairs within wave
    if ((tid & 32) == 0) part[wave * R_ + r] = acc;
    __syncthreads();

    const unsigned phase = (unsigned)((s >> 1) & 1);
    const int bsel = s & 1;

    if (tid < R_) {
      float sum = part[tid] + part[R_ + tid] + part[2 * R_ + tid] +
                  part[3 * R_ + tid] + xiv;
      // -0.0 guard: sign bit is the phase flag, must be 0 for values
      float h = (sum > 0.0f) ? sum : 0.0f;
      h_l[own_lo + tid] = h;                  // own rows: LDS-direct, no RTT
      hseq[s * H_ + own_lo + tid] = h;        // for rnn_post
      unsigned pk = __float_as_uint(h) | (phase << 31);
      // push to the 15 remote consumers' private mailboxes (fire-and-forget)
#pragma unroll
      for (int c = 0; c < G_; ++c) {
        if (c != b)
          __hip_atomic_store(&mbox[(c * 2 + bsel) * H_ + own_lo + tid], pk,
                             __ATOMIC_RELAXED, __HIP_MEMORY_SCOPE_AGENT);
      }
    }

    if (s == S_ - 1) break;                   // nothing to consume after last

    // prefetch next step's xi (hidden under poll RTT)
    if (tid < R_) xiv = xi[(s + 1) * H_ + own_lo + tid];

    // poll MY private mailbox only; both entries in flight concurrently
    unsigned* const buf = mbox + (b * 2 + bsel) * H_;
    bool need0 = !own0, need1 = !own1;
    unsigned p0, p1;
    while (need0 | need1) {
      if (need0)
        p0 = __hip_atomic_load(&buf[n0], __ATOMIC_RELAXED, __HIP_MEMORY_SCOPE_AGENT);
      if (need1)
        p1 = __hip_atomic_load(&buf[n1], __ATOMIC_RELAXED, __HIP_MEMORY_SCOPE_AGENT);
      if (need0 && (p0 >> 31) == phase) {
        h_l[n0] = __uint_as_float(p0 & 0x7fffffffu);
        need0 = false;
      }
      if (need1 && (p1 >> 31) == phase) {
        h_l[n1] = __uint_as_float(p1 & 0x7fffffffu);
        need1 = false;
      }
    }
    __syncthreads();
  }
}

__global__ __launch_bounds__(256) void rnn_post(
    const float* __restrict__ hseq, const float* __restrict__ W2,
    const float* __restrict__ b2, float* __restrict__ y) {
  const int t = blockIdx.x;
  const int tid = threadIdx.x;
  __shared__ float hl[H_];
  __shared__ float part[256];
  for (int n = tid; n < H_; n += 256) hl[n] = hseq[t * H_ + n];
  __syncthreads();
  const int o = tid >> 3;
  const int seg = tid & 7;
  float acc = 0.0f;
  if (o < O_) {
    const float4* wp = (const float4*)(W2 + o * H_ + seg * 64);
    const float4* hp = (const float4*)(hl + seg * 64);
#pragma unroll
    for (int j = 0; j < 16; ++j) {
      float4 w4 = wp[j];
      float4 h4 = hp[j];
      acc += w4.x * h4.x + w4.y * h4.y + w4.z * h4.z + w4.w * h4.w;
    }
  }
  part[tid] = acc;
  __syncthreads();
  if (tid < O_) {
    float sum = 0.0f;
#pragma unroll
    for (int j = 0; j < 8; ++j) sum += part[tid * 8 + j];
    y[t * O_ + tid] = sum + b2[tid];
  }
}

extern "C" void kernel_launch(void* const* d_in, const int* in_sizes, int n_in,
                              void* d_out, int out_size, void* d_ws, size_t ws_size,
                              hipStream_t stream) {
  const float* x    = (const float*)d_in[0];
  const float* W_ih = (const float*)d_in[1];
  const float* W_hh = (const float*)d_in[2];
  const float* b_ih = (const float*)d_in[3];
  const float* b_hh = (const float*)d_in[4];
  const float* W2   = (const float*)d_in[5];
  const float* b2   = (const float*)d_in[6];
  float* y = (float*)d_out;

  float* xi   = (float*)d_ws;                      // [512*512]
  float* hseq = xi + S_ * H_;                      // [512*512]
  unsigned* mbox = (unsigned*)(hseq + S_ * H_);    // [G_*2*512] mailboxes

  rnn_pre<<<dim3(S_, 2), 256, 0, stream>>>(x, W_ih, b_ih, b_hh, xi, mbox);
  rnn_seq<<<G_, 256, 0, stream>>>(W_hh, xi, hseq, mbox);
  rnn_post<<<S_, 256, 0, stream>>>(hseq, W2, b2, y);
}

// Round 5
// 819.637 us; speedup vs baseline: 1.3366x; 1.1182x over previous
//
#include <hip/hip_runtime.h>

// Problem: S=512, B=256, I=64, H=512, O=25.
// y depends only on batch row 255 (out[:, -1, :]) and the recurrence is
// per-row independent -> compute only row 255.
//
//   rnn_pre : xi[t][h] = x[t,255,:] . W_ih[h,:] + b_ih[h] + b_hh[h];
//             block (0,0) also re-inits the shared exchange buffer.
//   rnn_seq : 512 sequential steps h = relu(xi_t + W_hh h_prev) on G_=16
//             blocks, 512 threads each. Row layout: 16 lanes per row within
//             one wave (seg = lane&15), each thread holds 32 STRIDED columns
//             (cols 4*(seg+16j)+c) so LDS h-reads are broadcast/2-way (free)
//             and the reduce is 4 wave-local shfl_xor folds -- the finalizer
//             lane publishes IMMEDIATELY after its wave's dot (no block-wide
//             barrier before the store). h double-buffered in LDS -> exactly
//             one __syncthreads per step. Exchange: single shared mailbox
//             (R4 showed replication hurts), 32-bit values, generation in
//             the SIGN BIT (relu => h>=0 with -0.0 guard), double-buffered
//             by s&1, generation (s>>1)&1; progress invariant bounds skew
//             to <2 steps. One poll entry per thread, tight 1-load loop.
//   rnn_post: y[t] = h_t . W2^T + b2   (512x25)

#define S_ 512
#define B_ 256
#define I_ 64
#define H_ 512
#define O_ 25
#define G_ 16   // blocks in rnn_seq
#define R_ 32   // rows per block (H_/G_)
#define T_ 512  // threads per block in rnn_seq

__global__ __launch_bounds__(256) void rnn_pre(
    const float* __restrict__ x, const float* __restrict__ W_ih,
    const float* __restrict__ b_ih, const float* __restrict__ b_hh,
    float* __restrict__ xi, unsigned* __restrict__ mbox) {
  const int t = blockIdx.x;
  const int tid = threadIdx.x;
  const int o = blockIdx.y * 256 + tid;
  if (t == 0 && blockIdx.y == 0) {
    // init both shared buffers to sign=1 (not-ready for generation 0);
    // kernel boundary publishes to rnn_seq.
    for (int j = tid; j < 2 * H_; j += 256) mbox[j] = 0x80000000u;
  }
  __shared__ float xr[I_];
  if (tid < I_) xr[tid] = x[(t * B_ + (B_ - 1)) * I_ + tid];
  __syncthreads();
  float acc = b_ih[o] + b_hh[o];
  const float4* wp = (const float4*)(W_ih + o * I_);
#pragma unroll
  for (int j = 0; j < I_ / 4; ++j) {
    float4 w4 = wp[j];
    acc += w4.x * xr[4 * j] + w4.y * xr[4 * j + 1] + w4.z * xr[4 * j + 2] +
           w4.w * xr[4 * j + 3];
  }
  xi[t * H_ + o] = acc;
}

__global__ __launch_bounds__(T_) void rnn_seq(
    const float* __restrict__ W_hh, const float* __restrict__ xi,
    float* __restrict__ hseq, unsigned* __restrict__ mbox) {
  const int tid = threadIdx.x;
  const int b = blockIdx.x;
  const int lane = tid & 63;
  const int wv = tid >> 6;          // wave 0..7
  const int seg = lane & 15;        // 16 lanes per row
  const int row_l = wv * 4 + (lane >> 4);  // local row 0..31
  const int row = b * R_ + row_l;
  const int own_lo = b * R_;
  const bool fin = (seg == 0);      // finalizer lane for this row

  __shared__ float h_l[2][H_];      // double-buffered h

  // Thread's 32 STRIDED columns: float4 chunk j at element 4*(seg+16*j).
  // LDS bank of chunk j = (4*seg) % 32 -> segs s and s+8 share a bank quad
  // with 2 distinct addresses = 2-way = free; 4 row-lanes broadcast.
  float w[32];
  {
    const float4* wrow = (const float4*)(W_hh + row * H_);
#pragma unroll
    for (int j = 0; j < 8; ++j) {
      float4 v = wrow[seg + 16 * j];
      w[4 * j] = v.x; w[4 * j + 1] = v.y; w[4 * j + 2] = v.z; w[4 * j + 3] = v.w;
    }
  }
  for (int n = tid; n < H_; n += T_) h_l[0][n] = 0.0f;  // h_{-1} = 0

  float xiv = fin ? xi[row] : 0.0f;  // xi for step 0; later prefetched
  __syncthreads();

  // poll assignment: one remote entry per thread, skip own rows
  const int e = (tid < H_ - R_) ? (tid + ((tid >= own_lo) ? R_ : 0)) : -1;

  for (int s = 0; s < S_; ++s) {
    const float* hr = h_l[s & 1];
    float* hw = h_l[(s + 1) & 1];
    const unsigned phase = (unsigned)((s >> 1) & 1);
    unsigned* const buf = mbox + (s & 1) * H_;

    // partial dot over this thread's 32 strided cols, 4 accumulator chains
    float a0 = 0.f, a1 = 0.f, a2 = 0.f, a3 = 0.f;
    const float4* hp = (const float4*)hr;
#pragma unroll
    for (int j = 0; j < 8; ++j) {
      float4 hv = hp[seg + 16 * j];
      a0 = fmaf(w[4 * j + 0], hv.x, a0);
      a1 = fmaf(w[4 * j + 1], hv.y, a1);
      a2 = fmaf(w[4 * j + 2], hv.z, a2);
      a3 = fmaf(w[4 * j + 3], hv.w, a3);
    }
    float acc = (a0 + a1) + (a2 + a3);
    // wave-local fold over the 16 seg lanes (lane bits 0..3)
    acc += __shfl_xor(acc, 1, 64);
    acc += __shfl_xor(acc, 2, 64);
    acc += __shfl_xor(acc, 4, 64);
    acc += __shfl_xor(acc, 8, 64);

    // finalizer publishes IMMEDIATELY (wave-local; no block barrier first)
    if (fin) {
      float sum = acc + xiv;
      float h = (sum > 0.0f) ? sum : 0.0f;   // -0.0 guard (sign bit = phase)
      hw[row] = h;                            // own row: LDS-direct
      hseq[s * H_ + row] = h;                 // for rnn_post
      __hip_atomic_store(&buf[row], __float_as_uint(h) | (phase << 31),
                         __ATOMIC_RELAXED, __HIP_MEMORY_SCOPE_AGENT);
    }

    if (s == S_ - 1) break;                   // nothing to consume after last

    if (fin) xiv = xi[(s + 1) * H_ + row];    // prefetch, hidden under poll

    // tight single-entry poll
    if (e >= 0) {
      unsigned p;
      do {
        p = __hip_atomic_load(&buf[e], __ATOMIC_RELAXED, __HIP_MEMORY_SCOPE_AGENT);
      } while ((p >> 31) != phase);
      hw[e] = __uint_as_float(p & 0x7fffffffu);
    }
    __syncthreads();
  }
}

__global__ __launch_bounds__(256) void rnn_post(
    const float* __restrict__ hseq, const float* __restrict__ W2,
    const float* __restrict__ b2, float* __restrict__ y) {
  const int t = blockIdx.x;
  const int tid = threadIdx.x;
  __shared__ float hl[H_];
  __shared__ float part[256];
  for (int n = tid; n < H_; n += 256) hl[n] = hseq[t * H_ + n];
  __syncthreads();
  const int o = tid >> 3;
  const int seg = tid & 7;
  float acc = 0.0f;
  if (o < O_) {
    const float4* wp = (const float4*)(W2 + o * H_ + seg * 64);
    const float4* hp = (const float4*)(hl + seg * 64);
#pragma unroll
    for (int j = 0; j < 16; ++j) {
      float4 w4 = wp[j];
      float4 h4 = hp[j];
      acc += w4.x * h4.x + w4.y * h4.y + w4.z * h4.z + w4.w * h4.w;
    }
  }
  part[tid] = acc;
  __syncthreads();
  if (tid < O_) {
    float sum = 0.0f;
#pragma unroll
    for (int j = 0; j < 8; ++j) sum += part[tid * 8 + j];
    y[t * O_ + tid] = sum + b2[tid];
  }
}

extern "C" void kernel_launch(void* const* d_in, const int* in_sizes, int n_in,
                              void* d_out, int out_size, void* d_ws, size_t ws_size,
                              hipStream_t stream) {
  const float* x    = (const float*)d_in[0];
  const float* W_ih = (const float*)d_in[1];
  const float* W_hh = (const float*)d_in[2];
  const float* b_ih = (const float*)d_in[3];
  const float* b_hh = (const float*)d_in[4];
  const float* W2   = (const float*)d_in[5];
  const float* b2   = (const float*)d_in[6];
  float* y = (float*)d_out;

  float* xi   = (float*)d_ws;                      // [512*512]
  float* hseq = xi + S_ * H_;                      // [512*512]
  unsigned* mbox = (unsigned*)(hseq + S_ * H_);    // [2*512] shared mailbox

  rnn_pre<<<dim3(S_, 2), 256, 0, stream>>>(x, W_ih, b_ih, b_hh, xi, mbox);
  rnn_seq<<<G_, T_, 0, stream>>>(W_hh, xi, hseq, mbox);
  rnn_post<<<S_, 256, 0, stream>>>(hseq, W2, b2, y);
}